// Round 8
// baseline (100.134 us; speedup 1.0000x reference)
//
#include <hip/hip_runtime.h>
#include <hip/hip_bf16.h>

// SPP patch extraction, fused single-launch.
// feat (512,48,48) fp32; scales {4,6,8,10,12,14,16}, stride-2 SxS windows,
// adaptive max pool 7x7 -> (ny*nx, 512*49) per scale, concatenated.
//
// R8: barrier-free emit. Phases per block (scale, 8-ch chunk, iy):
//  P2: rp[row=c*7+py][x] = y-binned max, read direct from L1/L2 (input is
//      cache-resident), ONE barrier.
//  Emit: flat loop over (ix, j=c*49+py*7+px); one output element per
//      iteration, stored DIRECTLY to global as coalesced b32 (consecutive
//      lanes -> consecutive addresses; 16 lanes fill each 64B line). No LDS
//      round-trip, no in-loop __syncthreads -> no vmcnt(0) barrier drains;
//      stores stream continuously while VALU/LDS work hides under them.

#define HW 48
#define CSTR (HW * HW)   // 2304
#define POOL 7
#define PE 25088         // 512*49 elems per patch
#define CH 8             // channels per block
#define RPS 50           // rp row stride (floats)

constexpr int cdiv7(int x) { return (x + 6) / 7; }
constexpr int nyf(int S) { return (HW - S) / 2 + 1; }
constexpr int max_bin(int S) {
    int m = 0;
    for (int i = 0; i < POOL; ++i) {
        int a = (i * S) / POOL, b = cdiv7((i + 1) * S);
        if (b - a > m) m = b - a;
    }
    return m;
}

template <int S>
__device__ __forceinline__ void run_scale(int b, const float* __restrict__ feat,
                                          float* __restrict__ outp, float* rp) {
    constexpr int NX = nyf(S);
    constexpr int MB = max_bin(S);
    const int tid = threadIdx.x;
    const int iy = b >> 6;           // 64 chunks
    const int c0 = (b & 63) * CH;
    const int y0 = iy * 2;

    // ---- P2: rp[row][x] = y-binned max, direct from global (cache-hot) ----
    const float* fb = feat + (size_t)c0 * CSTR + y0 * HW;
    for (int t = tid; t < CH * POOL * HW; t += 256) {
        int c = t / (POOL * HW);
        int rem = t - c * (POOL * HW);
        int py = rem / HW;
        int x = rem - py * HW;
        int ay = (py * S) / POOL;
        int szy = cdiv7((py + 1) * S) - ay;
        const float* wb = fb + c * CSTR + ay * HW + x;
        float m = wb[0];
#pragma unroll
        for (int r = 1; r < MB; ++r)
            m = fmaxf(m, wb[min(r, szy - 1) * HW]);  // clamped dup rows ok
        rp[(c * POOL + py) * RPS + x] = m;
    }
    __syncthreads();                 // the only barrier

    // ---- Emit: one element per iteration, direct coalesced b32 stores ----
    constexpr int TOT = NX * CH * 49;      // NX*392
    float* obase = outp + (size_t)iy * NX * PE + (size_t)c0 * 49;
    int ix = 0, j = tid;             // tid < 392 always -> start at (0, tid)
    for (int k = tid; k < TOT; k += 256) {
        int row = j / 7;             // compile-time-magic divs (j < 392)
        int px = j - row * 7;
        int ax = (px * S) / POOL;
        int szx = cdiv7((px + 1) * S) - ax;
        const float* v = rp + row * RPS + 2 * ix + ax;
        float m = v[0];
#pragma unroll
        for (int q = 1; q < MB; ++q)
            m = fmaxf(m, v[min(q, szx - 1)]);        // clamped dup cols ok
        obase[(size_t)ix * PE + j] = m;
        j += 256;
        if (j >= CH * 49) { j -= CH * 49; ++ix; }
    }
}

__global__ __launch_bounds__(256) void spp_fused(const float* __restrict__ feat,
                                                 float* __restrict__ out) {
    __shared__ float rp[CH * POOL * RPS];   // 11.2 KB -> 8 blocks/CU
    int b = blockIdx.x;
    if (b < 1472)      run_scale<4>(b,         feat, out,                     rp);
    else if (b < 2880) run_scale<6>(b - 1472,  feat, out + (size_t)529  * PE, rp);
    else if (b < 4224) run_scale<8>(b - 2880,  feat, out + (size_t)1013 * PE, rp);
    else if (b < 5504) run_scale<10>(b - 4224, feat, out + (size_t)1454 * PE, rp);
    else if (b < 6720) run_scale<12>(b - 5504, feat, out + (size_t)1854 * PE, rp);
    else if (b < 7872) run_scale<14>(b - 6720, feat, out + (size_t)2215 * PE, rp);
    else               run_scale<16>(b - 7872, feat, out + (size_t)2539 * PE, rp);
}

extern "C" void kernel_launch(void* const* d_in, const int* in_sizes, int n_in,
                              void* d_out, int out_size, void* d_ws, size_t ws_size,
                              hipStream_t stream) {
    const float* feat = (const float*)d_in[0];
    float* out = (float*)d_out;
    spp_fused<<<8960, 256, 0, stream>>>(feat, out);
}

// Round 9
// 57.144 us; speedup vs baseline: 1.7523x; 1.7523x over previous
//
#include <hip/hip_runtime.h>
#include <hip/hip_bf16.h>

// SPP patch extraction, fused single-launch.
// feat (512,48,48) fp32; scales {4,6,8,10,12,14,16}, stride-2 SxS windows,
// adaptive max pool 7x7 -> (ny*nx, 512*49) per scale, concatenated.
//
// R9: wave-autonomous emit (no cross-wave sync after rp).
//  P2: rp[row=c*7+py][x] = y-binned max, direct from L1/L2; ONE barrier.
//  Then each wave owns patches ix = wave, wave+4, ... and a private 392-float
//  outb slice. Per patch: P3 (lanes 0-55 = rows; float2 rp reads, compile-time
//  px bins, 7 b32 LDS writes in output order) then P4 (float4 LDS read ->
//  global_store_dwordx4, dense 1KB/wave runs). DS ops are in-order within a
//  wave -> no barrier/waitcnt needed, only compiler reorder fences.
//  LDS 17.5 KB -> 8 blocks/CU (32 waves): stores stream continuously.

#define HW 48
#define CSTR (HW * HW)   // 2304
#define POOL 7
#define PE 25088         // 512*49 elems per patch
#define CH 8             // channels per block
#define RPS 50           // rp row stride (floats)

constexpr int cdiv7(int x) { return (x + 6) / 7; }
constexpr int nyf(int S) { return (HW - S) / 2 + 1; }
constexpr int max_bin(int S) {
    int m = 0;
    for (int i = 0; i < POOL; ++i) {
        int a = (i * S) / POOL, b = cdiv7((i + 1) * S);
        if (b - a > m) m = b - a;
    }
    return m;
}

template <int S>
__device__ __forceinline__ void run_scale(int b, const float* __restrict__ feat,
                                          float* __restrict__ outp,
                                          float* rp, float* owb) {
    constexpr int NX = nyf(S);
    constexpr int MB = max_bin(S);
    const int tid = threadIdx.x;
    const int iy = b >> 6;           // 64 chunks
    const int c0 = (b & 63) * CH;
    const int y0 = iy * 2;

    // ---- P2: rp[row][x] = y-binned max, direct from global (cache-hot) ----
    const float* fb = feat + (size_t)c0 * CSTR + y0 * HW;
    for (int t = tid; t < CH * POOL * HW; t += 256) {
        int c = t / (POOL * HW);
        int rem = t - c * (POOL * HW);
        int py = rem / HW;
        int x = rem - py * HW;
        int ay = (py * S) / POOL;
        int szy = cdiv7((py + 1) * S) - ay;
        const float* wb = fb + c * CSTR + ay * HW + x;
        float m = wb[0];
#pragma unroll
        for (int r = 1; r < MB; ++r)
            m = fmaxf(m, wb[min(r, szy - 1) * HW]);  // clamped dup rows ok
        rp[(c * POOL + py) * RPS + x] = m;
    }
    __syncthreads();                 // the only barrier

    // ---- wave-autonomous emit ----
    const int wv = tid >> 6;
    const int lane = tid & 63;
    float* myout = owb + wv * 392;   // private per-wave staging
    float* obase = outp + (size_t)iy * NX * PE + (size_t)c0 * 49;

    for (int ix = wv; ix < NX; ix += 4) {
        // P3: lanes 0..55 = rows (c*7+py); all bin indices compile-time
        if (lane < 56) {
            const float* v = rp + lane * RPS + 2 * ix;   // 8B-aligned
            float x[S];
#pragma unroll
            for (int k = 0; k < S / 2; ++k) {
                float2 p = *(const float2*)(v + 2 * k);
                x[2 * k] = p.x;
                x[2 * k + 1] = p.y;
            }
            float* ob = myout + lane * 7;                // output order
#pragma unroll
            for (int px = 0; px < POOL; ++px) {
                int ax = (px * S) / POOL;                // compile-time
                int bx = cdiv7((px + 1) * S);
                float m = x[ax];
#pragma unroll
                for (int k = ax + 1; k < bx; ++k) m = fmaxf(m, x[k]);
                ob[px] = m;
            }
        }
        asm volatile("" ::: "memory");  // keep P3 writes before P4 reads
        // P4: 98 float4 -> dense coalesced dwordx4 stores
        float* od = obase + (size_t)ix * PE;
        {
            float4 vv = *(const float4*)(myout + 4 * lane);
            *(float4*)(od + 4 * lane) = vv;
            int k2 = lane + 64;
            if (k2 < 98) {
                float4 v2 = *(const float4*)(myout + 4 * k2);
                *(float4*)(od + 4 * k2) = v2;
            }
        }
        asm volatile("" ::: "memory");  // keep P4 reads before next P3 writes
    }
}

__global__ __launch_bounds__(256) void spp_fused(const float* __restrict__ feat,
                                                 float* __restrict__ out) {
    __shared__ float rp[CH * POOL * RPS];        // 11.2 KB
    __shared__ __align__(16) float owb[4 * 392]; // 6.3 KB (per-wave slices)
    int b = blockIdx.x;
    if (b < 1472)      run_scale<4>(b,         feat, out,                     rp, owb);
    else if (b < 2880) run_scale<6>(b - 1472,  feat, out + (size_t)529  * PE, rp, owb);
    else if (b < 4224) run_scale<8>(b - 2880,  feat, out + (size_t)1013 * PE, rp, owb);
    else if (b < 5504) run_scale<10>(b - 4224, feat, out + (size_t)1454 * PE, rp, owb);
    else if (b < 6720) run_scale<12>(b - 5504, feat, out + (size_t)1854 * PE, rp, owb);
    else if (b < 7872) run_scale<14>(b - 6720, feat, out + (size_t)2215 * PE, rp, owb);
    else               run_scale<16>(b - 7872, feat, out + (size_t)2539 * PE, rp, owb);
}

extern "C" void kernel_launch(void* const* d_in, const int* in_sizes, int n_in,
                              void* d_out, int out_size, void* d_ws, size_t ws_size,
                              hipStream_t stream) {
    const float* feat = (const float*)d_in[0];
    float* out = (float*)d_out;
    spp_fused<<<8960, 256, 0, stream>>>(feat, out);
}

// Round 10
// 53.790 us; speedup vs baseline: 1.8616x; 1.0623x over previous
//
#include <hip/hip_runtime.h>
#include <hip/hip_bf16.h>

// SPP patch extraction, fused single-launch.
// feat (512,48,48) fp32; scales {4,6,8,10,12,14,16}, stride-2 SxS windows,
// adaptive max pool 7x7 -> (ny*nx, 512*49) per scale, concatenated.
//
// R10 = R9 (wave-autonomous emit) +
//  - heavy-first block ordering (S=16 segment first, S=4 last): block cost
//    varies ~2x across scales and the grid runs ~4.4 occupancy rounds, so
//    scheduling the long poles first tightens the tail round.
//  - P2 vectorized to float2 (halves load instrs + decode iterations).
// Structure: P2 builds rp[row=c*7+py][x] (y-binned max) once per block, one
// barrier; then each wave owns patches ix = wv, wv+4, ... with a private
// 392-float LDS slice: P3 x-pools (compile-time bins) into the slice, P4
// copies it out as dense dwordx4 stores. DS ops are wave-ordered -> no
// barrier in the emit loop; stores stream continuously.

#define HW 48
#define CSTR (HW * HW)   // 2304
#define POOL 7
#define PE 25088         // 512*49 elems per patch
#define CH 8             // channels per block
#define RPS 50           // rp row stride (floats)

constexpr int cdiv7(int x) { return (x + 6) / 7; }
constexpr int nyf(int S) { return (HW - S) / 2 + 1; }
constexpr int max_bin(int S) {
    int m = 0;
    for (int i = 0; i < POOL; ++i) {
        int a = (i * S) / POOL, b = cdiv7((i + 1) * S);
        if (b - a > m) m = b - a;
    }
    return m;
}

template <int S>
__device__ __forceinline__ void run_scale(int b, const float* __restrict__ feat,
                                          float* __restrict__ outp,
                                          float* rp, float* owb) {
    constexpr int NX = nyf(S);
    constexpr int MB = max_bin(S);
    const int tid = threadIdx.x;
    const int iy = b >> 6;           // 64 chunks
    const int c0 = (b & 63) * CH;
    const int y0 = iy * 2;

    // ---- P2: rp[row][x] = y-binned max, float2, direct from cache ----
    const float* fb = feat + (size_t)c0 * CSTR + y0 * HW;
    for (int t = tid; t < CH * POOL * (HW / 2); t += 256) {   // 1344
        int c = t / (POOL * 24);
        int rem = t - c * (POOL * 24);
        int py = rem / 24;
        int xl = rem - py * 24;                               // x = 2*xl
        int ay = (py * S) / POOL;
        int szy = cdiv7((py + 1) * S) - ay;
        const float* wb = fb + c * CSTR + ay * HW + 2 * xl;
        float2 m = *(const float2*)wb;
#pragma unroll
        for (int r = 1; r < MB; ++r) {
            float2 v = *(const float2*)(wb + min(r, szy - 1) * HW);
            m.x = fmaxf(m.x, v.x);
            m.y = fmaxf(m.y, v.y);
        }
        *(float2*)(rp + (c * POOL + py) * RPS + 2 * xl) = m;
    }
    __syncthreads();                 // the only barrier

    // ---- wave-autonomous emit ----
    const int wv = tid >> 6;
    const int lane = tid & 63;
    float* myout = owb + wv * 392;   // private per-wave staging
    float* obase = outp + (size_t)iy * NX * PE + (size_t)c0 * 49;

    for (int ix = wv; ix < NX; ix += 4) {
        // P3: lanes 0..55 = rows (c*7+py); all bin indices compile-time
        if (lane < 56) {
            const float* v = rp + lane * RPS + 2 * ix;   // 8B-aligned
            float x[S];
#pragma unroll
            for (int k = 0; k < S / 2; ++k) {
                float2 p = *(const float2*)(v + 2 * k);
                x[2 * k] = p.x;
                x[2 * k + 1] = p.y;
            }
            float* ob = myout + lane * 7;                // output order
#pragma unroll
            for (int px = 0; px < POOL; ++px) {
                int ax = (px * S) / POOL;                // compile-time
                int bx = cdiv7((px + 1) * S);
                float m = x[ax];
#pragma unroll
                for (int k = ax + 1; k < bx; ++k) m = fmaxf(m, x[k]);
                ob[px] = m;
            }
        }
        asm volatile("" ::: "memory");  // keep P3 writes before P4 reads
        // P4: 98 float4 -> dense coalesced dwordx4 stores
        float* od = obase + (size_t)ix * PE;
        {
            float4 vv = *(const float4*)(myout + 4 * lane);
            *(float4*)(od + 4 * lane) = vv;
            int k2 = lane + 64;
            if (k2 < 98) {
                float4 v2 = *(const float4*)(myout + 4 * k2);
                *(float4*)(od + 4 * k2) = v2;
            }
        }
        asm volatile("" ::: "memory");  // keep P4 reads before next P3 writes
    }
}

__global__ __launch_bounds__(256) void spp_fused(const float* __restrict__ feat,
                                                 float* __restrict__ out) {
    __shared__ float rp[CH * POOL * RPS];        // 11.2 KB
    __shared__ __align__(16) float owb[4 * 392]; // 6.3 KB (per-wave slices)
    int b = blockIdx.x;
    // Heavy-first: S=16,14,12,10,8,6,4. Output offsets stay in scale order.
    if (b < 1088)      run_scale<16>(b,         feat, out + (size_t)2539 * PE, rp, owb);
    else if (b < 2240) run_scale<14>(b - 1088,  feat, out + (size_t)2215 * PE, rp, owb);
    else if (b < 3456) run_scale<12>(b - 2240,  feat, out + (size_t)1854 * PE, rp, owb);
    else if (b < 4736) run_scale<10>(b - 3456,  feat, out + (size_t)1454 * PE, rp, owb);
    else if (b < 6080) run_scale<8>(b - 4736,   feat, out + (size_t)1013 * PE, rp, owb);
    else if (b < 7488) run_scale<6>(b - 6080,   feat, out + (size_t)529  * PE, rp, owb);
    else               run_scale<4>(b - 7488,   feat, out,                     rp, owb);
}

extern "C" void kernel_launch(void* const* d_in, const int* in_sizes, int n_in,
                              void* d_out, int out_size, void* d_ws, size_t ws_size,
                              hipStream_t stream) {
    const float* feat = (const float*)d_in[0];
    float* out = (float*)d_out;
    spp_fused<<<8960, 256, 0, stream>>>(feat, out);
}